// Round 1
// baseline (145.312 us; speedup 1.0000x reference)
//
#include <hip/hip_runtime.h>
#include <math.h>

#define BB 8
#define NN 2048
#define INC 256
#define NH 4
#define CC 128
#define NE 65536
#define CAP 128
#define MROWS (BB*NN)
#define BN_EPS 1e-5f

// ---------------- edge-index layout detect (int64 vs int32) ----------------
__global__ void k_detect(const int* __restrict__ ei, int* __restrict__ flag) {
  if (threadIdx.x == 0 && blockIdx.x == 0) {
    int nz = 0;
    for (int i = 1; i < 128; i += 2) nz |= (ei[i] != 0);
    *flag = nz ? 0 : 1;   // 1 => int64 layout
  }
}

__device__ inline void load_edge(const void* ei, int is64, int e, int& s, int& d) {
  if (is64) {
    const long long* p = (const long long*)ei;
    s = (int)p[e]; d = (int)p[NE + e];
  } else {
    const int* p = (const int*)ei;
    s = p[e]; d = p[NE + e];
  }
}

// ---------------- Wm = mean_h W[:, h*C+c];  Wa[i][j] = sum_c W[i,hC+c]*a_half[c] ----
__global__ __launch_bounds__(128) void k_prep_w(const float* __restrict__ W,
                                                const float* __restrict__ a,
                                                float* __restrict__ Wm,
                                                float* __restrict__ Wa) {
  int i = blockIdx.x;        // input channel 0..255
  int c = threadIdx.x;       // 0..127
  const float* Wr = W + (size_t)i * (NH * CC);
  float w0 = Wr[0*CC + c], w1 = Wr[1*CC + c], w2 = Wr[2*CC + c], w3 = Wr[3*CC + c];
  Wm[(size_t)i*CC + c] = 0.25f * (w0 + w1 + w2 + w3);
  float asrc = a[c], adst = a[CC + c];
  float vals[8] = {w0*asrc, w1*asrc, w2*asrc, w3*asrc,
                   w0*adst, w1*adst, w2*adst, w3*adst};
  __shared__ float red[128];
  for (int j = 0; j < 8; ++j) {
    red[c] = vals[j];
    __syncthreads();
    for (int off = 64; off > 0; off >>= 1) {
      if (c < off) red[c] += red[c + off];
      __syncthreads();
    }
    if (c == 0) Wa[i*8 + j] = red[0];
    __syncthreads();
  }
}

// ---------------- hm = x @ Wm   [16384,256]@[256,128] f32 ----------------
__global__ __launch_bounds__(256) void k_gemm(const float* __restrict__ x,
                                              const float* __restrict__ Wm,
                                              float* __restrict__ hm) {
  __shared__ float xs[64][33];
  __shared__ float ws[32][CC];
  int tid = threadIdx.x;
  int tx = tid & 15, ty = tid >> 4;
  int m0 = blockIdx.x * 64;
  float acc[4][8];
  #pragma unroll
  for (int i = 0; i < 4; ++i)
    #pragma unroll
    for (int j = 0; j < 8; ++j) acc[i][j] = 0.0f;

  for (int k0 = 0; k0 < INC; k0 += 32) {
    #pragma unroll
    for (int i = 0; i < 8; ++i) {
      int idx = tid + i * 256;
      int r = idx >> 5, kk = idx & 31;
      xs[r][kk] = x[(size_t)(m0 + r) * INC + k0 + kk];
    }
    #pragma unroll
    for (int i = 0; i < 16; ++i) {
      int idx = tid + i * 256;
      int kk = idx >> 7, c = idx & 127;
      ws[kk][c] = Wm[(size_t)(k0 + kk) * CC + c];
    }
    __syncthreads();
    #pragma unroll
    for (int kk = 0; kk < 32; ++kk) {
      float av[4], bv[8];
      #pragma unroll
      for (int i = 0; i < 4; ++i) av[i] = xs[ty*4 + i][kk];
      #pragma unroll
      for (int j = 0; j < 8; ++j) bv[j] = ws[kk][tx*8 + j];
      #pragma unroll
      for (int i = 0; i < 4; ++i)
        #pragma unroll
        for (int j = 0; j < 8; ++j) acc[i][j] += av[i] * bv[j];
    }
    __syncthreads();
  }
  #pragma unroll
  for (int i = 0; i < 4; ++i) {
    float* dst = hm + (size_t)(m0 + ty*4 + i) * CC + tx*8;
    #pragma unroll
    for (int j = 0; j < 8; ++j) dst[j] = acc[i][j];
  }
}

// ---------------- s = x @ Wa   [16384,256]@[256,8], one wave per row -------
__global__ __launch_bounds__(256) void k_s(const float* __restrict__ x,
                                           const float* __restrict__ Wa,
                                           float* __restrict__ s) {
  int lane = threadIdx.x & 63;
  int wv = threadIdx.x >> 6;
  int row = blockIdx.x * 4 + wv;
  float4 xv = ((const float4*)(x + (size_t)row * INC))[lane];
  float acc[8];
  #pragma unroll
  for (int j = 0; j < 8; ++j) acc[j] = 0.0f;
  #pragma unroll
  for (int t = 0; t < 4; ++t) {
    int i = lane * 4 + t;
    float xt = (t == 0) ? xv.x : (t == 1) ? xv.y : (t == 2) ? xv.z : xv.w;
    const float* war = Wa + i * 8;
    #pragma unroll
    for (int j = 0; j < 8; ++j) acc[j] += xt * war[j];
  }
  #pragma unroll
  for (int off = 32; off > 0; off >>= 1)
    #pragma unroll
    for (int j = 0; j < 8; ++j) acc[j] += __shfl_down(acc[j], off, 64);
  if (lane == 0) {
    #pragma unroll
    for (int j = 0; j < 8; ++j) s[(size_t)row * 8 + j] = acc[j];
  }
}

// ---------------- e_avg[b,e] = mean_h leaky(s_src + s_dst) ----------------
__global__ __launch_bounds__(256) void k_edge(const void* __restrict__ ei,
                                              const int* __restrict__ flag,
                                              const float* __restrict__ s,
                                              float* __restrict__ eavg) {
  int e = blockIdx.x * 256 + threadIdx.x;
  int is64 = *flag;
  int src, dst;
  load_edge(ei, is64, e, src, dst);
  #pragma unroll
  for (int b = 0; b < BB; ++b) {
    const float* ps = s + (size_t)(b * NN + src) * 8;
    const float* pd = s + (size_t)(b * NN + dst) * 8 + 4;
    float sum = 0.0f;
    #pragma unroll
    for (int h = 0; h < 4; ++h) {
      float v = ps[h] + pd[h];
      sum += (v > 0.0f) ? v : 0.2f * v;
    }
    eavg[(size_t)b * NE + e] = 0.25f * sum;
  }
}

// ---------------- per-dst-row edge list build ----------------
__global__ __launch_bounds__(256) void k_fill(const void* __restrict__ ei,
                                              const int* __restrict__ flag,
                                              int* __restrict__ row_cnt,
                                              int* __restrict__ row_src,
                                              int* __restrict__ row_eid) {
  int e = blockIdx.x * 256 + threadIdx.x;
  int is64 = *flag;
  int src, dst;
  load_edge(ei, is64, e, src, dst);
  int pos = atomicAdd(&row_cnt[dst], 1);
  if (pos < CAP) {
    row_src[dst * CAP + pos] = src;
    row_eid[dst * CAP + pos] = e;
  }
}

// ------- sort each row by edge id, dedupe same-src keeping max eid (last-wins) ---
__global__ __launch_bounds__(256) void k_sortdedupe(const int* __restrict__ row_cnt,
                                                    int* __restrict__ row_src,
                                                    int* __restrict__ row_eid,
                                                    int* __restrict__ uniq_cnt) {
  __shared__ int ls[4][CAP], le[4][CAP], ss[4][CAP], se[4][CAP], kf[4][CAP];
  int tid = threadIdx.x;
  int wv = tid >> 6, lane = tid & 63;
  int d = blockIdx.x * 4 + wv;
  int k = row_cnt[d]; if (k > CAP) k = CAP;
  for (int i = lane; i < k; i += 64) {
    ls[wv][i] = row_src[d * CAP + i];
    le[wv][i] = row_eid[d * CAP + i];
  }
  __syncthreads();
  for (int i = lane; i < k; i += 64) {
    int eid = le[wv][i]; int r = 0;
    for (int j = 0; j < k; ++j) r += (le[wv][j] < eid) ? 1 : 0;
    ss[wv][r] = ls[wv][i]; se[wv][r] = eid;
  }
  __syncthreads();
  for (int pp = lane; pp < k; pp += 64) {
    int sv = ss[wv][pp]; int keep = 1;
    for (int q = pp + 1; q < k; ++q) if (ss[wv][q] == sv) { keep = 0; break; }
    kf[wv][pp] = keep;
  }
  __syncthreads();
  if (lane == 0) {
    int m = 0;
    for (int pp = 0; pp < k; ++pp) {
      if (kf[wv][pp]) {
        row_src[d * CAP + m] = ss[wv][pp];
        row_eid[d * CAP + m] = se[wv][pp];
        ++m;
      }
    }
    uniq_cnt[d] = m;
  }
}

// ---------------- softmax over row + weighted aggregation ----------------
__global__ __launch_bounds__(128) void k_agg(const int* __restrict__ uniq_cnt,
                                             const int* __restrict__ row_src,
                                             const int* __restrict__ row_eid,
                                             const float* __restrict__ eavg,
                                             const float* __restrict__ hm,
                                             float* __restrict__ hout) {
  int d = blockIdx.x, b = blockIdx.y, tid = threadIdx.x;
  int k = uniq_cnt[d];
  __shared__ float wgt[CAP];
  __shared__ int sidx[CAP];
  __shared__ float red[CAP];
  float v = -INFINITY;
  if (tid < k) {
    int eid = row_eid[d * CAP + tid];
    sidx[tid] = row_src[d * CAP + tid];
    v = eavg[(size_t)b * NE + eid];
  }
  red[tid] = v;
  __syncthreads();
  #pragma unroll
  for (int off = 64; off > 0; off >>= 1) {
    if (tid < off) red[tid] = fmaxf(red[tid], red[tid + off]);
    __syncthreads();
  }
  float mx = red[0];
  __syncthreads();
  float ew = (tid < k) ? expf(v - mx) : 0.0f;
  wgt[tid] = ew;
  red[tid] = ew;
  __syncthreads();
  #pragma unroll
  for (int off = 64; off > 0; off >>= 1) {
    if (tid < off) red[tid] += red[tid + off];
    __syncthreads();
  }
  float inv = (k > 0) ? 1.0f / red[0] : 0.0f;
  float acc = 0.0f;
  for (int j = 0; j < k; ++j) {
    acc += wgt[j] * hm[(size_t)(b * NN + sidx[j]) * CC + tid];
  }
  hout[(size_t)(b * NN + d) * CC + tid] = acc * inv;
}

// ---------------- BN stats: one block per channel (deterministic) ----------
__global__ __launch_bounds__(256) void k_bnstat(const float* __restrict__ hout,
                                                const float* __restrict__ gamma,
                                                const float* __restrict__ beta,
                                                float* __restrict__ bn) {
  int c = blockIdx.x, tid = threadIdx.x;
  float sum = 0.0f, sq = 0.0f;
  for (int i = tid; i < MROWS; i += 256) {
    float v = hout[(size_t)i * CC + c];
    sum += v; sq += v * v;
  }
  __shared__ float rs[256], rq[256];
  rs[tid] = sum; rq[tid] = sq;
  __syncthreads();
  for (int off = 128; off > 0; off >>= 1) {
    if (tid < off) { rs[tid] += rs[tid + off]; rq[tid] += rq[tid + off]; }
    __syncthreads();
  }
  if (tid == 0) {
    float mean = rs[0] / (float)MROWS;
    float var = rq[0] / (float)MROWS - mean * mean;
    if (var < 0.0f) var = 0.0f;
    float scale = gamma[c] / sqrtf(var + BN_EPS);
    bn[c] = scale;
    bn[CC + c] = beta[c] - mean * scale;
  }
}

// ---------------- normalize + ELU ----------------
__global__ __launch_bounds__(256) void k_bnelu(const float* __restrict__ hout,
                                               const float* __restrict__ bn,
                                               float* __restrict__ out) {
  int i = blockIdx.x * 256 + threadIdx.x;
  int c = i & (CC - 1);
  float y = hout[i] * bn[c] + bn[CC + c];
  out[i] = (y > 0.0f) ? y : expm1f(y);
}

extern "C" void kernel_launch(void* const* d_in, const int* in_sizes, int n_in,
                              void* d_out, int out_size, void* d_ws, size_t ws_size,
                              hipStream_t stream) {
  const float* x     = (const float*)d_in[0];
  const void*  ei    = d_in[1];
  const float* W     = (const float*)d_in[2];
  const float* a     = (const float*)d_in[3];
  const float* gamma = (const float*)d_in[4];
  const float* beta  = (const float*)d_in[5];
  float* out = (float*)d_out;

  char* p = (char*)d_ws;
  float* hm   = (float*)p; p += (size_t)MROWS * CC * 4;   // 8 MB
  float* hout = (float*)p; p += (size_t)MROWS * CC * 4;   // 8 MB
  float* eavg = (float*)p; p += (size_t)BB * NE * 4;      // 2 MB
  float* s    = (float*)p; p += (size_t)MROWS * 8 * 4;    // 512 KB
  float* Wm   = (float*)p; p += (size_t)INC * CC * 4;     // 128 KB
  float* Wa   = (float*)p; p += (size_t)INC * 8 * 4;      // 8 KB
  float* bn   = (float*)p; p += 256 * 4;
  int* flag   = (int*)p;   p += 256;
  int* row_cnt  = (int*)p; p += NN * 4;
  int* uniq_cnt = (int*)p; p += NN * 4;
  int* row_src  = (int*)p; p += (size_t)NN * CAP * 4;     // 1 MB
  int* row_eid  = (int*)p; p += (size_t)NN * CAP * 4;     // 1 MB

  hipMemsetAsync(row_cnt, 0, NN * 4, stream);
  k_detect<<<1, 64, 0, stream>>>((const int*)ei, flag);
  k_prep_w<<<INC, 128, 0, stream>>>(W, a, Wm, Wa);
  k_gemm<<<MROWS / 64, 256, 0, stream>>>(x, Wm, hm);
  k_s<<<MROWS / 4, 256, 0, stream>>>(x, Wa, s);
  k_edge<<<NE / 256, 256, 0, stream>>>(ei, flag, s, eavg);
  k_fill<<<NE / 256, 256, 0, stream>>>(ei, flag, row_cnt, row_src, row_eid);
  k_sortdedupe<<<NN / 4, 256, 0, stream>>>(row_cnt, row_src, row_eid, uniq_cnt);
  k_agg<<<dim3(NN, BB), 128, 0, stream>>>(uniq_cnt, row_src, row_eid, eavg, hm, hout);
  k_bnstat<<<CC, 256, 0, stream>>>(hout, gamma, beta, bn);
  k_bnelu<<<(MROWS * CC) / 256, 256, 0, stream>>>(hout, bn, out);
}

// Round 2
// 116.950 us; speedup vs baseline: 1.2425x; 1.2425x over previous
//
#include <hip/hip_runtime.h>
#include <math.h>

#define BB 8
#define NN 2048
#define INC 256
#define NH 4
#define CC 128
#define NE 65536
#define CAP 128
#define MROWS (BB*NN)
#define BN_EPS 1e-5f

typedef unsigned int uint32;
typedef unsigned short ushort16;

__device__ inline ushort f2bf(float f) {
  uint32 u = __float_as_uint(f);
  u += 0x7fffu + ((u >> 16) & 1u);
  return (ushort)(u >> 16);
}
__device__ inline float bf2f(ushort h) {
  return __uint_as_float(((uint32)h) << 16);
}

__device__ inline void load_edge(const void* ei, int is64, int e, int& s, int& d) {
  if (is64) {
    const long long* p = (const long long*)ei;
    s = (int)p[e]; d = (int)p[NE + e];
  } else {
    const int* p = (const int*)ei;
    s = p[e]; d = p[NE + e];
  }
}

// ---- prep: Wm = mean_h W ; Wa[i][j] = sum_c W[i,hC+c]*a_half[c] ; detect ; zero cnt ----
__global__ __launch_bounds__(128) void k_prep_w(const float* __restrict__ W,
                                                const float* __restrict__ a,
                                                const int* __restrict__ ei32,
                                                float* __restrict__ Wm,
                                                float* __restrict__ Wa,
                                                int* __restrict__ flag,
                                                int* __restrict__ row_cnt) {
  int i = blockIdx.x;        // input channel 0..255
  int c = threadIdx.x;       // 0..127
  if (i == 0 && c == 0) {
    int nz = 0;
    for (int t = 1; t < 128; t += 2) nz |= (ei32[t] != 0);
    *flag = nz ? 0 : 1;      // 1 => int64 layout
  }
  {
    int g = i * 128 + c;
    if (g < NN) row_cnt[g] = 0;
  }
  const float* Wr = W + (size_t)i * (NH * CC);
  float w0 = Wr[0*CC + c], w1 = Wr[1*CC + c], w2 = Wr[2*CC + c], w3 = Wr[3*CC + c];
  Wm[(size_t)i*CC + c] = 0.25f * (w0 + w1 + w2 + w3);
  float asrc = a[c], adst = a[CC + c];
  float vals[8] = {w0*asrc, w1*asrc, w2*asrc, w3*asrc,
                   w0*adst, w1*adst, w2*adst, w3*adst};
  __shared__ float red[128];
  for (int j = 0; j < 8; ++j) {
    red[c] = vals[j];
    __syncthreads();
    for (int off = 64; off > 0; off >>= 1) {
      if (c < off) red[c] += red[c + off];
      __syncthreads();
    }
    if (c == 0) Wa[i*8 + j] = red[0];
    __syncthreads();
  }
}

// ---- hm(bf16) = x @ Wm   [16384,256]@[256,128] ----
__global__ __launch_bounds__(256) void k_gemm(const float* __restrict__ x,
                                              const float* __restrict__ Wm,
                                              ushort* __restrict__ hm) {
  __shared__ float xsT[32][68];   // [kk][row], pad 68 (272B, 16B-aligned rows)
  __shared__ float ws[32][128];   // [kk][c]
  int tid = threadIdx.x;
  int tx = tid & 15, ty = tid >> 4;   // tx: col-oct (8 cols), ty: row-quad (4 rows)
  int m0 = blockIdx.x * 64;
  float acc[4][8];
  #pragma unroll
  for (int i = 0; i < 4; ++i)
    #pragma unroll
    for (int j = 0; j < 8; ++j) acc[i][j] = 0.0f;

  int sr = tid >> 3;        // 0..31
  int skq = tid & 7;        // 0..7 -> k-chunk of 4
  int wkk = tid >> 5;       // 0..7
  int wc4 = (tid & 31) * 4;

  for (int k0 = 0; k0 < INC; k0 += 32) {
    #pragma unroll
    for (int i = 0; i < 2; ++i) {
      int r = sr + 32 * i;
      float4 v = *(const float4*)(x + (size_t)(m0 + r) * INC + k0 + skq * 4);
      xsT[skq*4 + 0][r] = v.x;
      xsT[skq*4 + 1][r] = v.y;
      xsT[skq*4 + 2][r] = v.z;
      xsT[skq*4 + 3][r] = v.w;
    }
    #pragma unroll
    for (int i = 0; i < 4; ++i) {
      int kk = wkk + i * 8;
      float4 v = *(const float4*)(Wm + (size_t)(k0 + kk) * CC + wc4);
      *(float4*)&ws[kk][wc4] = v;
    }
    __syncthreads();
    #pragma unroll
    for (int kk = 0; kk < 32; ++kk) {
      float4 av = *(const float4*)&xsT[kk][ty*4];
      float4 b0 = *(const float4*)&ws[kk][tx*8];
      float4 b1 = *(const float4*)&ws[kk][tx*8 + 4];
      float bv[8] = {b0.x,b0.y,b0.z,b0.w,b1.x,b1.y,b1.z,b1.w};
      float av4[4] = {av.x,av.y,av.z,av.w};
      #pragma unroll
      for (int i = 0; i < 4; ++i)
        #pragma unroll
        for (int j = 0; j < 8; ++j) acc[i][j] += av4[i] * bv[j];
    }
    __syncthreads();
  }
  #pragma unroll
  for (int i = 0; i < 4; ++i) {
    int row = m0 + ty*4 + i;
    uint32 pk[4];
    #pragma unroll
    for (int j = 0; j < 4; ++j) {
      pk[j] = (uint32)f2bf(acc[i][2*j]) | ((uint32)f2bf(acc[i][2*j+1]) << 16);
    }
    *(uint4*)(hm + (size_t)row * CC + tx*8) = make_uint4(pk[0],pk[1],pk[2],pk[3]);
  }
}

// ---- s = x @ Wa   [16384,256]@[256,8], one wave per row ----
__global__ __launch_bounds__(256) void k_s(const float* __restrict__ x,
                                           const float* __restrict__ Wa,
                                           float* __restrict__ s) {
  int lane = threadIdx.x & 63;
  int wv = threadIdx.x >> 6;
  int row = blockIdx.x * 4 + wv;
  float4 xv = ((const float4*)(x + (size_t)row * INC))[lane];
  float acc[8];
  #pragma unroll
  for (int j = 0; j < 8; ++j) acc[j] = 0.0f;
  #pragma unroll
  for (int t = 0; t < 4; ++t) {
    int i = lane * 4 + t;
    float xt = (t == 0) ? xv.x : (t == 1) ? xv.y : (t == 2) ? xv.z : xv.w;
    const float* war = Wa + i * 8;
    #pragma unroll
    for (int j = 0; j < 8; ++j) acc[j] += xt * war[j];
  }
  #pragma unroll
  for (int off = 32; off > 0; off >>= 1)
    #pragma unroll
    for (int j = 0; j < 8; ++j) acc[j] += __shfl_down(acc[j], off, 64);
  if (lane == 0) {
    #pragma unroll
    for (int j = 0; j < 8; ++j) s[(size_t)row * 8 + j] = acc[j];
  }
}

// ---- e_avg[b,e] = mean_h leaky(s_src + s_dst) ----
__global__ __launch_bounds__(256) void k_edge(const void* __restrict__ ei,
                                              const int* __restrict__ flag,
                                              const float* __restrict__ s,
                                              float* __restrict__ eavg) {
  int e = blockIdx.x * 256 + threadIdx.x;
  int is64 = *flag;
  int src, dst;
  load_edge(ei, is64, e, src, dst);
  #pragma unroll
  for (int b = 0; b < BB; ++b) {
    float4 ps = ((const float4*)s)[(size_t)(b * NN + src) * 2];
    float4 pd = ((const float4*)s)[(size_t)(b * NN + dst) * 2 + 1];
    float vs[4] = {ps.x+pd.x, ps.y+pd.y, ps.z+pd.z, ps.w+pd.w};
    float sum = 0.0f;
    #pragma unroll
    for (int h = 0; h < 4; ++h) {
      float v = vs[h];
      sum += (v > 0.0f) ? v : 0.2f * v;
    }
    eavg[(size_t)b * NE + e] = 0.25f * sum;
  }
}

// ---- per-dst-row edge list build ----
__global__ __launch_bounds__(256) void k_fill(const void* __restrict__ ei,
                                              const int* __restrict__ flag,
                                              int* __restrict__ row_cnt,
                                              int* __restrict__ row_src,
                                              int* __restrict__ row_eid) {
  int e = blockIdx.x * 256 + threadIdx.x;
  int is64 = *flag;
  int src, dst;
  load_edge(ei, is64, e, src, dst);
  int pos = atomicAdd(&row_cnt[dst], 1);
  if (pos < CAP) {
    row_src[dst * CAP + pos] = src;
    row_eid[dst * CAP + pos] = e;
  }
}

// ---- sort each row by eid, dedupe same-src keeping max eid (last-wins) ----
__global__ __launch_bounds__(256) void k_sortdedupe(const int* __restrict__ row_cnt,
                                                    int* __restrict__ row_src,
                                                    int* __restrict__ row_eid,
                                                    int* __restrict__ uniq_cnt) {
  __shared__ int ls[4][CAP], le[4][CAP], ss[4][CAP], se[4][CAP], kf[4][CAP];
  int tid = threadIdx.x;
  int wv = tid >> 6, lane = tid & 63;
  int d = blockIdx.x * 4 + wv;
  int k = row_cnt[d]; if (k > CAP) k = CAP;
  for (int i = lane; i < k; i += 64) {
    ls[wv][i] = row_src[d * CAP + i];
    le[wv][i] = row_eid[d * CAP + i];
  }
  __syncthreads();
  for (int i = lane; i < k; i += 64) {
    int eid = le[wv][i]; int r = 0;
    for (int j = 0; j < k; ++j) r += (le[wv][j] < eid) ? 1 : 0;
    ss[wv][r] = ls[wv][i]; se[wv][r] = eid;
  }
  __syncthreads();
  for (int pp = lane; pp < k; pp += 64) {
    int sv = ss[wv][pp]; int keep = 1;
    for (int q = pp + 1; q < k; ++q) if (ss[wv][q] == sv) { keep = 0; break; }
    kf[wv][pp] = keep;
  }
  __syncthreads();
  if (lane == 0) {
    int m = 0;
    for (int pp = 0; pp < k; ++pp) {
      if (kf[wv][pp]) {
        row_src[d * CAP + m] = ss[wv][pp];
        row_eid[d * CAP + m] = se[wv][pp];
        ++m;
      }
    }
    uniq_cnt[d] = m;
  }
}

// ---- softmax over row + weighted aggregation (bf16 hm gather) ----
__global__ __launch_bounds__(128) void k_agg(const int* __restrict__ uniq_cnt,
                                             const int* __restrict__ row_src,
                                             const int* __restrict__ row_eid,
                                             const float* __restrict__ eavg,
                                             const ushort* __restrict__ hm,
                                             float* __restrict__ hout) {
  int d = blockIdx.x, b = blockIdx.y, tid = threadIdx.x;
  int lane = tid & 63, wv = tid >> 6;
  int k = uniq_cnt[d];
  __shared__ float wgt[CAP];
  __shared__ int sidx[CAP];
  __shared__ float xm[2], xs[2];
  float v = -INFINITY;
  if (tid < k) {
    sidx[tid] = row_src[d * CAP + tid];
    v = eavg[(size_t)b * NE + row_eid[d * CAP + tid]];
  }
  float m = v;
  #pragma unroll
  for (int off = 32; off > 0; off >>= 1) m = fmaxf(m, __shfl_xor(m, off, 64));
  if (lane == 0) xm[wv] = m;
  __syncthreads();
  float mx = fmaxf(xm[0], xm[1]);
  float ew = (tid < k) ? expf(v - mx) : 0.0f;
  wgt[tid] = ew;
  float ssum = ew;
  #pragma unroll
  for (int off = 32; off > 0; off >>= 1) ssum += __shfl_xor(ssum, off, 64);
  if (lane == 0) xs[wv] = ssum;
  __syncthreads();
  float tot = xs[0] + xs[1];
  float inv = (k > 0) ? 1.0f / tot : 0.0f;
  float acc = 0.0f;
  for (int j = 0; j < k; ++j) {
    acc += wgt[j] * bf2f(hm[(size_t)(b * NN + sidx[j]) * CC + tid]);
  }
  hout[(size_t)(b * NN + d) * CC + tid] = acc * inv;
}

// ---- BN stage 1: coalesced per-64-row partial sums ----
__global__ __launch_bounds__(256) void k_bnpart(const float* __restrict__ hout,
                                                float* __restrict__ partS,
                                                float* __restrict__ partQ) {
  int blk = blockIdx.x, tid = threadIdx.x;
  int c = tid & 127, half = tid >> 7;
  float sum = 0.0f, sq = 0.0f;
  int r0 = blk * 64 + half * 32;
  for (int i = 0; i < 32; ++i) {
    float v = hout[(size_t)(r0 + i) * CC + c];
    sum += v; sq += v * v;
  }
  __shared__ float rs[256], rq[256];
  rs[tid] = sum; rq[tid] = sq;
  __syncthreads();
  if (tid < 128) {
    partS[blk * CC + c] = rs[c] + rs[c + 128];
    partQ[blk * CC + c] = rq[c] + rq[c + 128];
  }
}

// ---- BN stage 2: per-channel final reduce -> scale/shift ----
__global__ __launch_bounds__(256) void k_bnstat2(const float* __restrict__ partS,
                                                 const float* __restrict__ partQ,
                                                 const float* __restrict__ gamma,
                                                 const float* __restrict__ beta,
                                                 float* __restrict__ bn) {
  int c = blockIdx.x, t = threadIdx.x;
  float s1 = partS[(size_t)t * CC + c];
  float q1 = partQ[(size_t)t * CC + c];
  __shared__ float rs[256], rq[256];
  rs[t] = s1; rq[t] = q1;
  __syncthreads();
  for (int off = 128; off > 0; off >>= 1) {
    if (t < off) { rs[t] += rs[t + off]; rq[t] += rq[t + off]; }
    __syncthreads();
  }
  if (t == 0) {
    float mean = rs[0] / (float)MROWS;
    float var = rq[0] / (float)MROWS - mean * mean;
    if (var < 0.0f) var = 0.0f;
    float scale = gamma[c] / sqrtf(var + BN_EPS);
    bn[c] = scale;
    bn[CC + c] = beta[c] - mean * scale;
  }
}

// ---- normalize + ELU ----
__global__ __launch_bounds__(256) void k_bnelu(const float* __restrict__ hout,
                                               const float* __restrict__ bn,
                                               float* __restrict__ out) {
  int i = blockIdx.x * 256 + threadIdx.x;
  int c = i & (CC - 1);
  float y = hout[i] * bn[c] + bn[CC + c];
  out[i] = (y > 0.0f) ? y : expm1f(y);
}

extern "C" void kernel_launch(void* const* d_in, const int* in_sizes, int n_in,
                              void* d_out, int out_size, void* d_ws, size_t ws_size,
                              hipStream_t stream) {
  const float* x     = (const float*)d_in[0];
  const void*  ei    = d_in[1];
  const float* W     = (const float*)d_in[2];
  const float* a     = (const float*)d_in[3];
  const float* gamma = (const float*)d_in[4];
  const float* beta  = (const float*)d_in[5];
  float* out = (float*)d_out;

  char* p = (char*)d_ws;
  ushort* hm  = (ushort*)p; p += (size_t)MROWS * CC * 2;  // 4 MB (bf16)
  float* hout = (float*)p; p += (size_t)MROWS * CC * 4;   // 8 MB
  float* eavg = (float*)p; p += (size_t)BB * NE * 4;      // 2 MB
  float* s    = (float*)p; p += (size_t)MROWS * 8 * 4;    // 512 KB
  float* Wm   = (float*)p; p += (size_t)INC * CC * 4;     // 128 KB
  float* Wa   = (float*)p; p += (size_t)INC * 8 * 4;      // 8 KB
  float* bn   = (float*)p; p += 256 * 4;
  float* partS = (float*)p; p += 256 * CC * 4;            // 128 KB
  float* partQ = (float*)p; p += 256 * CC * 4;            // 128 KB
  int* flag   = (int*)p;   p += 256;
  int* row_cnt  = (int*)p; p += NN * 4;
  int* uniq_cnt = (int*)p; p += NN * 4;
  int* row_src  = (int*)p; p += (size_t)NN * CAP * 4;     // 1 MB
  int* row_eid  = (int*)p; p += (size_t)NN * CAP * 4;     // 1 MB

  k_prep_w<<<INC, 128, 0, stream>>>(W, a, (const int*)ei, Wm, Wa, flag, row_cnt);
  k_gemm<<<MROWS / 64, 256, 0, stream>>>(x, Wm, hm);
  k_s<<<MROWS / 4, 256, 0, stream>>>(x, Wa, s);
  k_edge<<<NE / 256, 256, 0, stream>>>(ei, flag, s, eavg);
  k_fill<<<NE / 256, 256, 0, stream>>>(ei, flag, row_cnt, row_src, row_eid);
  k_sortdedupe<<<NN / 4, 256, 0, stream>>>(row_cnt, row_src, row_eid, uniq_cnt);
  k_agg<<<dim3(NN, BB), 128, 0, stream>>>(uniq_cnt, row_src, row_eid, eavg, hm, hout);
  k_bnpart<<<256, 256, 0, stream>>>(hout, partS, partQ);
  k_bnstat2<<<CC, 256, 0, stream>>>(partS, partQ, gamma, beta, bn);
  k_bnelu<<<(MROWS * CC) / 256, 256, 0, stream>>>(hout, bn, out);
}

// Round 3
// 77.192 us; speedup vs baseline: 1.8825x; 1.5151x over previous
//
#include <hip/hip_runtime.h>
#include <math.h>

#define BB 8
#define NN 2048
#define INC 256
#define NH 4
#define CC 128
#define NE 65536
#define CAP 128
#define MROWS (BB*NN)
#define BN_EPS 1e-5f
#define NT 9              // output col-tiles of 16 (8 -> hm, 1 -> s+pad)
#define NKC 8             // K chunks of 32 (K=256)
#define NFRAG (NT*NKC*64) // 4608 pre-packed Wm fragments

typedef unsigned int uint32;
typedef __attribute__((ext_vector_type(8))) short short8;
typedef __attribute__((ext_vector_type(4))) float f32x4;

__device__ inline ushort f2bf(float f) {
  uint32 u = __float_as_uint(f);
  u += 0x7fffu + ((u >> 16) & 1u);
  return (ushort)(u >> 16);
}
__device__ inline float bf2f(ushort h) {
  return __uint_as_float(((uint32)h) << 16);
}

__device__ inline void load_edge(const void* ei, int is64, int e, int& s, int& d) {
  if (is64) {
    const long long* p = (const long long*)ei;
    s = (int)p[e]; d = (int)p[NE + e];
  } else {
    const int* p = (const int*)ei;
    s = p[e]; d = p[NE + e];
  }
}

// ---- prep: Wm = mean_h W ; Wa[i][j] = sum_c W[i,hC+c]*a_half[c] ; detect ; zero cnt ----
__global__ __launch_bounds__(128) void k_prep_w(const float* __restrict__ W,
                                                const float* __restrict__ a,
                                                const int* __restrict__ ei32,
                                                float* __restrict__ Wm,
                                                float* __restrict__ Wa,
                                                int* __restrict__ flag,
                                                int* __restrict__ row_cnt) {
  int i = blockIdx.x;        // input channel 0..255
  int c = threadIdx.x;       // 0..127
  if (i == 0 && c == 0) {
    int nz = 0;
    for (int t = 1; t < 128; t += 2) nz |= (ei32[t] != 0);
    *flag = nz ? 0 : 1;      // 1 => int64 layout
  }
  {
    int g = i * 128 + c;
    if (g < NN) row_cnt[g] = 0;
  }
  const float* Wr = W + (size_t)i * (NH * CC);
  float w0 = Wr[0*CC + c], w1 = Wr[1*CC + c], w2 = Wr[2*CC + c], w3 = Wr[3*CC + c];
  Wm[(size_t)i*CC + c] = 0.25f * (w0 + w1 + w2 + w3);
  float asrc = a[c], adst = a[CC + c];
  float vals[8] = {w0*asrc, w1*asrc, w2*asrc, w3*asrc,
                   w0*adst, w1*adst, w2*adst, w3*adst};
  __shared__ float red[128];
  for (int j = 0; j < 8; ++j) {
    red[c] = vals[j];
    __syncthreads();
    for (int off = 64; off > 0; off >>= 1) {
      if (c < off) red[c] += red[c + off];
      __syncthreads();
    }
    if (c == 0) Wa[i*8 + j] = red[0];
    __syncthreads();
  }
}

// ---- pack A-operand (WmT|WaT) MFMA fragments in exact lane order ----
// frag f = (t, kc, lane): 8 bf16 of B-col c = 16t+(lane&15), k = 32kc+8*(lane>>4)+j
__global__ __launch_bounds__(256) void k_pack(const float* __restrict__ Wm,
                                              const float* __restrict__ Wa,
                                              uint4* __restrict__ pack) {
  int f = blockIdx.x * 256 + threadIdx.x;
  if (f >= NFRAG) return;
  int lane = f & 63;
  int kc = (f >> 6) & 7;
  int t = f >> 9;
  int c = t * 16 + (lane & 15);
  int kb = kc * 32 + (lane >> 4) * 8;
  uint32 h[8];
  #pragma unroll
  for (int j = 0; j < 8; ++j) {
    int k = kb + j;
    float v = 0.0f;
    if (c < CC) v = Wm[(size_t)k * CC + c];
    else if (c < CC + 8) v = Wa[k * 8 + (c - CC)];
    h[j] = (uint32)f2bf(v);
  }
  uint4 u;
  u.x = h[0] | (h[1] << 16);
  u.y = h[2] | (h[3] << 16);
  u.z = h[4] | (h[5] << 16);
  u.w = h[6] | (h[7] << 16);
  pack[f] = u;
}

// ---- MFMA GEMM: hm(bf16)[16384][128] = x @ Wm ; s(f32)[16384][8] = x @ Wa ----
// swapped operands: D[ch][xrow] per 16x16 tile; x frags straight from global.
__global__ __launch_bounds__(256) void k_gemm(const float* __restrict__ x,
                                              const uint4* __restrict__ pack,
                                              ushort* __restrict__ hm,
                                              float* __restrict__ s) {
  extern __shared__ uint4 lds_pack[];
  int tid = threadIdx.x;
  #pragma unroll
  for (int i = 0; i < NFRAG / 256; ++i)
    lds_pack[i * 256 + tid] = pack[i * 256 + tid];

  int lane = tid & 63, wv = tid >> 6;
  int g = lane >> 4;
  int xrow = blockIdx.x * 64 + wv * 16 + (lane & 15);
  const float* xr = x + (size_t)xrow * INC;

  f32x4 xa[16];
  #pragma unroll
  for (int kc = 0; kc < 8; ++kc) {
    xa[2*kc]   = *(const f32x4*)(xr + kc * 32 + g * 8);
    xa[2*kc+1] = *(const f32x4*)(xr + kc * 32 + g * 8 + 4);
  }
  short8 xf[8];
  #pragma unroll
  for (int kc = 0; kc < 8; ++kc) {
    short8 t;
    t[0] = (short)f2bf(xa[2*kc][0]);
    t[1] = (short)f2bf(xa[2*kc][1]);
    t[2] = (short)f2bf(xa[2*kc][2]);
    t[3] = (short)f2bf(xa[2*kc][3]);
    t[4] = (short)f2bf(xa[2*kc+1][0]);
    t[5] = (short)f2bf(xa[2*kc+1][1]);
    t[6] = (short)f2bf(xa[2*kc+1][2]);
    t[7] = (short)f2bf(xa[2*kc+1][3]);
    xf[kc] = t;
  }
  __syncthreads();

  f32x4 acc[NT];
  #pragma unroll
  for (int t = 0; t < NT; ++t) acc[t] = (f32x4)(0.0f);

  const short8* fr = (const short8*)lds_pack;
  #pragma unroll
  for (int kc = 0; kc < NKC; ++kc) {
    #pragma unroll
    for (int t = 0; t < NT; ++t) {
      short8 af = fr[(t * NKC + kc) * 64 + lane];
      acc[t] = __builtin_amdgcn_mfma_f32_16x16x32_bf16(af, xf[kc], acc[t], 0, 0, 0);
    }
  }

  // D layout: row(ch-in-tile) = 4*g + reg, col(xrow-in-wave) = lane&15
  ushort* hrow = hm + (size_t)xrow * CC;
  #pragma unroll
  for (int t = 0; t < 8; ++t) {
    uint32 p0 = (uint32)f2bf(acc[t][0]) | ((uint32)f2bf(acc[t][1]) << 16);
    uint32 p1 = (uint32)f2bf(acc[t][2]) | ((uint32)f2bf(acc[t][3]) << 16);
    *(uint2*)(hrow + t * 16 + g * 4) = make_uint2(p0, p1);
  }
  if (g < 2) {
    *(f32x4*)(s + (size_t)xrow * 8 + g * 4) = acc[8];
  }
}

// ---- fused: e_avg per edge/batch + per-dst-row list build ----
__global__ __launch_bounds__(256) void k_edgefill(const void* __restrict__ ei,
                                                  const int* __restrict__ flag,
                                                  const float* __restrict__ s,
                                                  float* __restrict__ eavg,
                                                  int* __restrict__ row_cnt,
                                                  int* __restrict__ row_src,
                                                  int* __restrict__ row_eid) {
  int e = blockIdx.x * 256 + threadIdx.x;
  int is64 = *flag;
  int src, dst;
  load_edge(ei, is64, e, src, dst);
  #pragma unroll
  for (int b = 0; b < BB; ++b) {
    float4 ps = ((const float4*)s)[(size_t)(b * NN + src) * 2];
    float4 pd = ((const float4*)s)[(size_t)(b * NN + dst) * 2 + 1];
    float vs[4] = {ps.x+pd.x, ps.y+pd.y, ps.z+pd.z, ps.w+pd.w};
    float sum = 0.0f;
    #pragma unroll
    for (int h = 0; h < 4; ++h) {
      float v = vs[h];
      sum += (v > 0.0f) ? v : 0.2f * v;
    }
    eavg[(size_t)b * NE + e] = 0.25f * sum;
  }
  int pos = atomicAdd(&row_cnt[dst], 1);
  if (pos < CAP) {
    row_src[dst * CAP + pos] = src;
    row_eid[dst * CAP + pos] = e;
  }
}

// ---- sort each row by eid, dedupe same-src keeping max eid (last-wins) ----
__global__ __launch_bounds__(256) void k_sortdedupe(const int* __restrict__ row_cnt,
                                                    int* __restrict__ row_src,
                                                    int* __restrict__ row_eid,
                                                    int* __restrict__ uniq_cnt) {
  __shared__ int ls[4][CAP], le[4][CAP], ss[4][CAP], se[4][CAP], kf[4][CAP];
  int tid = threadIdx.x;
  int wv = tid >> 6, lane = tid & 63;
  int d = blockIdx.x * 4 + wv;
  int k = row_cnt[d]; if (k > CAP) k = CAP;
  for (int i = lane; i < k; i += 64) {
    ls[wv][i] = row_src[d * CAP + i];
    le[wv][i] = row_eid[d * CAP + i];
  }
  __syncthreads();
  for (int i = lane; i < k; i += 64) {
    int eid = le[wv][i]; int r = 0;
    for (int j = 0; j < k; ++j) r += (le[wv][j] < eid) ? 1 : 0;
    ss[wv][r] = ls[wv][i]; se[wv][r] = eid;
  }
  __syncthreads();
  for (int pp = lane; pp < k; pp += 64) {
    int sv = ss[wv][pp]; int keep = 1;
    for (int q = pp + 1; q < k; ++q) if (ss[wv][q] == sv) { keep = 0; break; }
    kf[wv][pp] = keep;
  }
  __syncthreads();
  if (lane == 0) {
    int m = 0;
    for (int pp = 0; pp < k; ++pp) {
      if (kf[wv][pp]) {
        row_src[d * CAP + m] = ss[wv][pp];
        row_eid[d * CAP + m] = se[wv][pp];
        ++m;
      }
    }
    uniq_cnt[d] = m;
  }
}

// ---- softmax + aggregation: one wave per (b,d), lane owns a channel pair ----
__global__ __launch_bounds__(256) void k_agg(const int* __restrict__ uniq_cnt,
                                             const int* __restrict__ row_src,
                                             const int* __restrict__ row_eid,
                                             const float* __restrict__ eavg,
                                             const uint32* __restrict__ hm32,
                                             uint32* __restrict__ hout) {
  int tid = threadIdx.x, lane = tid & 63, wv = tid >> 6;
  int d = blockIdx.x * 4 + wv, b = blockIdx.y;
  __shared__ float swgt[4][CAP];
  __shared__ int ssrc[4][CAP];
  int k = uniq_cnt[d];
  float v0 = -INFINITY, v1 = -INFINITY;
  int i0 = 0, i1 = 0;
  if (lane < k) {
    i0 = row_src[d * CAP + lane];
    v0 = eavg[(size_t)b * NE + row_eid[d * CAP + lane]];
  }
  if (lane + 64 < k) {
    i1 = row_src[d * CAP + lane + 64];
    v1 = eavg[(size_t)b * NE + row_eid[d * CAP + lane + 64]];
  }
  float m = fmaxf(v0, v1);
  #pragma unroll
  for (int off = 32; off > 0; off >>= 1) m = fmaxf(m, __shfl_xor(m, off, 64));
  float e0 = (lane < k) ? expf(v0 - m) : 0.0f;
  float e1 = (lane + 64 < k) ? expf(v1 - m) : 0.0f;
  float sum = e0 + e1;
  #pragma unroll
  for (int off = 32; off > 0; off >>= 1) sum += __shfl_xor(sum, off, 64);
  float inv = (k > 0) ? 1.0f / sum : 0.0f;
  if (lane < k)      { swgt[wv][lane] = e0;      ssrc[wv][lane] = i0; }
  if (lane + 64 < k) { swgt[wv][lane + 64] = e1; ssrc[wv][lane + 64] = i1; }
  __syncthreads();
  float a0 = 0.0f, a1 = 0.0f;
  const uint32* hb = hm32 + (size_t)b * NN * (CC / 2);
  #pragma unroll 4
  for (int j = 0; j < k; ++j) {
    float w = swgt[wv][j];
    int sj = ssrc[wv][j];
    uint32 u = hb[(size_t)sj * (CC / 2) + lane];
    a0 += w * bf2f((ushort)(u & 0xffffu));
    a1 += w * bf2f((ushort)(u >> 16));
  }
  uint32 o = (uint32)f2bf(a0 * inv) | ((uint32)f2bf(a1 * inv) << 16);
  hout[((size_t)b * NN + d) * (CC / 2) + lane] = o;
}

// ---- BN stage 1: coalesced per-128-row partials (bf16 hout, uint loads) ----
__global__ __launch_bounds__(256) void k_bnpart(const uint32* __restrict__ hout,
                                                float* __restrict__ partS,
                                                float* __restrict__ partQ) {
  int blk = blockIdx.x, tid = threadIdx.x;
  int cp = tid & 63;       // channel pair
  int grp = tid >> 6;      // 0..3
  float s0 = 0, q0 = 0, s1 = 0, q1 = 0;
  for (int i = 0; i < 32; ++i) {
    int row = blk * 128 + grp * 32 + i;
    uint32 u = hout[(size_t)row * 64 + cp];
    float v0 = bf2f((ushort)(u & 0xffffu));
    float v1 = bf2f((ushort)(u >> 16));
    s0 += v0; q0 += v0 * v0; s1 += v1; q1 += v1 * v1;
  }
  __shared__ f32x4 red[256];
  f32x4 r; r[0] = s0; r[1] = q0; r[2] = s1; r[3] = q1;
  red[tid] = r;
  __syncthreads();
  if (grp == 0) {
    f32x4 t = red[cp] + red[cp + 64] + red[cp + 128] + red[cp + 192];
    partS[blk * CC + 2 * cp]     = t[0];
    partQ[blk * CC + 2 * cp]     = t[1];
    partS[blk * CC + 2 * cp + 1] = t[2];
    partQ[blk * CC + 2 * cp + 1] = t[3];
  }
}

// ---- BN stage 2: per-channel final reduce -> scale/shift ----
__global__ __launch_bounds__(128) void k_bnstat2(const float* __restrict__ partS,
                                                 const float* __restrict__ partQ,
                                                 const float* __restrict__ gamma,
                                                 const float* __restrict__ beta,
                                                 float* __restrict__ bn) {
  int c = blockIdx.x, t = threadIdx.x;
  __shared__ float rs[128], rq[128];
  rs[t] = partS[(size_t)t * CC + c];
  rq[t] = partQ[(size_t)t * CC + c];
  __syncthreads();
  for (int off = 64; off > 0; off >>= 1) {
    if (t < off) { rs[t] += rs[t + off]; rq[t] += rq[t + off]; }
    __syncthreads();
  }
  if (t == 0) {
    float mean = rs[0] / (float)MROWS;
    float var = rq[0] / (float)MROWS - mean * mean;
    if (var < 0.0f) var = 0.0f;
    float scale = gamma[c] / sqrtf(var + BN_EPS);
    bn[c] = scale;
    bn[CC + c] = beta[c] - mean * scale;
  }
}

// ---- normalize + ELU (bf16 in, f32 out) ----
__global__ __launch_bounds__(256) void k_bnelu(const uint32* __restrict__ hout,
                                               const float* __restrict__ bn,
                                               float* __restrict__ out) {
  int p = blockIdx.x * 256 + threadIdx.x;   // pair index
  int cp = p & 63;
  uint32 u = hout[p];
  float y0 = bf2f((ushort)(u & 0xffffu)) * bn[2*cp]     + bn[CC + 2*cp];
  float y1 = bf2f((ushort)(u >> 16))     * bn[2*cp + 1] + bn[CC + 2*cp + 1];
  float2 o;
  o.x = (y0 > 0.0f) ? y0 : expm1f(y0);
  o.y = (y1 > 0.0f) ? y1 : expm1f(y1);
  *(float2*)(out + 2 * (size_t)p) = o;
}

extern "C" void kernel_launch(void* const* d_in, const int* in_sizes, int n_in,
                              void* d_out, int out_size, void* d_ws, size_t ws_size,
                              hipStream_t stream) {
  const float* x     = (const float*)d_in[0];
  const void*  ei    = d_in[1];
  const float* W     = (const float*)d_in[2];
  const float* a     = (const float*)d_in[3];
  const float* gamma = (const float*)d_in[4];
  const float* beta  = (const float*)d_in[5];
  float* out = (float*)d_out;

  char* p = (char*)d_ws;
  ushort* hm   = (ushort*)p; p += (size_t)MROWS * CC * 2;  // 4 MB (bf16)
  uint32* hout = (uint32*)p; p += (size_t)MROWS * CC * 2;  // 4 MB (bf16 pairs)
  float* eavg = (float*)p; p += (size_t)BB * NE * 4;       // 2 MB
  float* s    = (float*)p; p += (size_t)MROWS * 8 * 4;     // 512 KB
  float* Wm   = (float*)p; p += (size_t)INC * CC * 4;      // 128 KB
  float* Wa   = (float*)p; p += (size_t)INC * 8 * 4;       // 8 KB
  uint4* pack = (uint4*)p; p += (size_t)NFRAG * 16;        // 72 KB
  float* partS = (float*)p; p += 128 * CC * 4;             // 64 KB
  float* partQ = (float*)p; p += 128 * CC * 4;             // 64 KB
  float* bn   = (float*)p; p += 256 * 4;
  int* flag   = (int*)p;   p += 256;
  int* row_cnt  = (int*)p; p += NN * 4;
  int* uniq_cnt = (int*)p; p += NN * 4;
  int* row_src  = (int*)p; p += (size_t)NN * CAP * 4;      // 1 MB
  int* row_eid  = (int*)p; p += (size_t)NN * CAP * 4;      // 1 MB

  k_prep_w<<<INC, 128, 0, stream>>>(W, a, (const int*)ei, Wm, Wa, flag, row_cnt);
  k_pack<<<(NFRAG + 255) / 256, 256, 0, stream>>>(Wm, Wa, pack);
  k_gemm<<<MROWS / 64, 256, NFRAG * 16, stream>>>(x, pack, hm, s);
  k_edgefill<<<NE / 256, 256, 0, stream>>>(ei, flag, s, eavg, row_cnt, row_src, row_eid);
  k_sortdedupe<<<NN / 4, 256, 0, stream>>>(row_cnt, row_src, row_eid, uniq_cnt);
  k_agg<<<dim3(NN / 4, BB), 256, 0, stream>>>(uniq_cnt, row_src, row_eid, eavg,
                                              (const uint32*)hm, hout);
  k_bnpart<<<MROWS / 128, 256, 0, stream>>>(hout, partS, partQ);
  k_bnstat2<<<CC, 128, 0, stream>>>(partS, partQ, gamma, beta, bn);
  k_bnelu<<<(MROWS * CC / 2) / 256, 256, 0, stream>>>(hout, bn, out);
}

// Round 4
// 67.097 us; speedup vs baseline: 2.1657x; 1.1504x over previous
//
#include <hip/hip_runtime.h>
#include <math.h>

#define BB 8
#define NN 2048
#define INC 256
#define CC 128
#define NE 65536
#define CAP 128
#define MROWS (BB*NN)
#define BN_EPS 1e-5f
#define NT 9              // output col-tiles of 16 (8 -> hm, 1 -> s+pad)
#define NKC 8             // K chunks of 32 (K=256)
#define NFRAG (NT*NKC*64) // 4608 pre-packed fragments

typedef unsigned int uint32;
typedef unsigned long long u64;
typedef __attribute__((ext_vector_type(8))) short short8;
typedef __attribute__((ext_vector_type(4))) float f32x4;

__device__ inline ushort f2bf(float f) {
  uint32 u = __float_as_uint(f);
  u += 0x7fffu + ((u >> 16) & 1u);
  return (ushort)(u >> 16);
}
__device__ inline float bf2f(ushort h) {
  return __uint_as_float(((uint32)h) << 16);
}

__device__ inline void load_edge(const void* ei, int is64, int e, int& s, int& d) {
  if (is64) {
    const long long* p = (const long long*)ei;
    s = (int)p[e]; d = (int)p[NE + e];
  } else {
    const int* p = (const int*)ei;
    s = p[e]; d = p[NE + e];
  }
}

// ---- prep: W -> packed MFMA fragments (Wm mean-head | Wa att cols) ----
// block m owns input rows i in [8m, 8m+8) == fragment k-slice kb=8m
// (kc = m>>2, g = m&3); writes 144 frags: t=0..8 x l16=0..15.
__global__ __launch_bounds__(256) void k_prep(const float* __restrict__ W,
                                              const float* __restrict__ a,
                                              const int* __restrict__ ei32,
                                              uint4* __restrict__ pack,
                                              int* __restrict__ flag,
                                              int* __restrict__ row_cnt) {
  __shared__ float Wl[8][520];
  __shared__ float Wms[8][132];
  __shared__ float Was[8][8];
  __shared__ float av[256];
  int m = blockIdx.x, tid = threadIdx.x;
  if (m < 8) row_cnt[m * 256 + tid] = 0;
  if (m == 0 && tid == 0) {
    int nz = 0;
    for (int t = 1; t < 128; t += 2) nz |= (ei32[t] != 0);
    *flag = nz ? 0 : 1;      // 1 => int64 layout
  }
  av[tid] = a[tid];
  const float4* Wg = (const float4*)(W + (size_t)m * 8 * 512);
  #pragma unroll
  for (int i = 0; i < 4; ++i) {
    int idx = tid + i * 256;           // 0..1023 float4s = 8 rows x 128
    int r = idx >> 7, c4 = idx & 127;
    *(float4*)&Wl[r][c4 * 4] = Wg[idx];
  }
  __syncthreads();
  {
    int c = tid & 127, half = tid >> 7;
    #pragma unroll
    for (int ii = 0; ii < 4; ++ii) {
      int r = half * 4 + ii;
      Wms[r][c] = 0.25f * (Wl[r][c] + Wl[r][128 + c] + Wl[r][256 + c] + Wl[r][384 + c]);
    }
  }
  {
    int i8 = tid >> 5, c2 = tid & 31;
    float p[8];
    #pragma unroll
    for (int j = 0; j < 8; ++j) p[j] = 0.0f;
    #pragma unroll
    for (int t4 = 0; t4 < 4; ++t4) {
      int cc = c2 + t4 * 32;
      float asrc = av[cc], adst = av[128 + cc];
      #pragma unroll
      for (int h = 0; h < 4; ++h) {
        float w = Wl[i8][h * 128 + cc];
        p[h] += w * asrc;
        p[4 + h] += w * adst;
      }
    }
    #pragma unroll
    for (int off = 16; off > 0; off >>= 1)
      #pragma unroll
      for (int j = 0; j < 8; ++j) p[j] += __shfl_xor(p[j], off, 64);
    if (c2 < 8) Was[i8][c2] = p[c2];
  }
  __syncthreads();
  if (tid < 144) {
    int t = tid >> 4, l16 = tid & 15;
    int cch = t * 16 + l16;
    int kc = m >> 2, g = m & 3;
    uint32 h[8];
    #pragma unroll
    for (int j = 0; j < 8; ++j) {
      float v = 0.0f;
      if (cch < CC) v = Wms[j][cch];
      else if (cch < CC + 8) v = Was[j][cch - CC];
      h[j] = (uint32)f2bf(v);
    }
    uint4 u;
    u.x = h[0] | (h[1] << 16);
    u.y = h[2] | (h[3] << 16);
    u.z = h[4] | (h[5] << 16);
    u.w = h[6] | (h[7] << 16);
    pack[(t * NKC + kc) * 64 + g * 16 + l16] = u;
  }
}

// ---- MFMA GEMM: hm(bf16)[16384][128] = x @ Wm ; s(f32)[16384][8] = x @ Wa ----
// swapped operands; A-fragments read straight from global (L2-hot 72 KB).
__global__ __launch_bounds__(256) void k_gemm(const float* __restrict__ x,
                                              const uint4* __restrict__ pack,
                                              ushort* __restrict__ hm,
                                              float* __restrict__ s) {
  int tid = threadIdx.x;
  int lane = tid & 63, wv = tid >> 6;
  int g = lane >> 4;
  int xrow = blockIdx.x * 64 + wv * 16 + (lane & 15);
  const float* xr = x + (size_t)xrow * INC;

  short8 xf[8];
  #pragma unroll
  for (int kc = 0; kc < 8; ++kc) {
    f32x4 xa = *(const f32x4*)(xr + kc * 32 + g * 8);
    f32x4 xb = *(const f32x4*)(xr + kc * 32 + g * 8 + 4);
    short8 t;
    t[0] = (short)f2bf(xa[0]); t[1] = (short)f2bf(xa[1]);
    t[2] = (short)f2bf(xa[2]); t[3] = (short)f2bf(xa[3]);
    t[4] = (short)f2bf(xb[0]); t[5] = (short)f2bf(xb[1]);
    t[6] = (short)f2bf(xb[2]); t[7] = (short)f2bf(xb[3]);
    xf[kc] = t;
  }

  f32x4 acc[NT];
  #pragma unroll
  for (int t = 0; t < NT; ++t) acc[t] = (f32x4)(0.0f);

  const short8* fr = (const short8*)pack;
  #pragma unroll
  for (int kc = 0; kc < NKC; ++kc) {
    #pragma unroll
    for (int t = 0; t < NT; ++t) {
      short8 af = fr[(t * NKC + kc) * 64 + lane];
      acc[t] = __builtin_amdgcn_mfma_f32_16x16x32_bf16(af, xf[kc], acc[t], 0, 0, 0);
    }
  }

  // D layout: row(ch-in-tile) = 4*g + reg, col(xrow-in-wave) = lane&15
  ushort* hrow = hm + (size_t)xrow * CC;
  #pragma unroll
  for (int t = 0; t < 8; ++t) {
    uint32 p0 = (uint32)f2bf(acc[t][0]) | ((uint32)f2bf(acc[t][1]) << 16);
    uint32 p1 = (uint32)f2bf(acc[t][2]) | ((uint32)f2bf(acc[t][3]) << 16);
    *(uint2*)(hrow + t * 16 + g * 4) = make_uint2(p0, p1);
  }
  if (g < 2) {
    *(f32x4*)(s + (size_t)xrow * 8 + g * 4) = acc[8];
  }
}

// ---- fused: e_avg[e][b] (coalesced) + per-dst-row list build ----
__global__ __launch_bounds__(256) void k_edgefill(const void* __restrict__ ei,
                                                  const int* __restrict__ flag,
                                                  const float* __restrict__ s,
                                                  float* __restrict__ eavgT,
                                                  int* __restrict__ row_cnt,
                                                  int* __restrict__ row_src,
                                                  int* __restrict__ row_eid) {
  int e = blockIdx.x * 256 + threadIdx.x;
  int is64 = *flag;
  int src, dst;
  load_edge(ei, is64, e, src, dst);
  float ev[8];
  #pragma unroll
  for (int b = 0; b < BB; ++b) {
    float4 ps = ((const float4*)s)[(size_t)(b * NN + src) * 2];
    float4 pd = ((const float4*)s)[(size_t)(b * NN + dst) * 2 + 1];
    float vs[4] = {ps.x+pd.x, ps.y+pd.y, ps.z+pd.z, ps.w+pd.w};
    float sum = 0.0f;
    #pragma unroll
    for (int h = 0; h < 4; ++h) {
      float v = vs[h];
      sum += (v > 0.0f) ? v : 0.2f * v;
    }
    ev[b] = 0.25f * sum;
  }
  *(float4*)(eavgT + (size_t)e * 8)     = make_float4(ev[0], ev[1], ev[2], ev[3]);
  *(float4*)(eavgT + (size_t)e * 8 + 4) = make_float4(ev[4], ev[5], ev[6], ev[7]);
  int pos = atomicAdd(&row_cnt[dst], 1);
  if (pos < CAP) {
    row_src[dst * CAP + pos] = src;
    row_eid[dst * CAP + pos] = e;
  }
}

// ---- fused sort+dedupe+softmax+aggregate: one block per dst row, all batches ----
__global__ __launch_bounds__(256) void k_agg(const int* __restrict__ row_cnt,
                                             const int* __restrict__ row_src,
                                             const int* __restrict__ row_eid,
                                             const float* __restrict__ eavgT,
                                             const uint32* __restrict__ hm32,
                                             uint32* __restrict__ hout) {
  __shared__ int rsrc[CAP], reid[CAP];   // raw, then compacted
  __shared__ int ssrc[CAP], seid[CAP];   // eid-sorted
  __shared__ float swgt[4][CAP];
  __shared__ int wcnt[2];
  int d = blockIdx.x, tid = threadIdx.x;
  int lane = tid & 63, wv = tid >> 6;
  int k0 = row_cnt[d]; if (k0 > CAP) k0 = CAP;

  if (tid < k0) {
    rsrc[tid] = row_src[d * CAP + tid];
    reid[tid] = row_eid[d * CAP + tid];
  }
  __syncthreads();
  // rank-sort by eid (eids are unique within a row)
  if (tid < k0) {
    int e = reid[tid], r = 0;
    for (int q = 0; q < k0; ++q) r += (reid[q] < e) ? 1 : 0;
    ssrc[r] = rsrc[tid]; seid[r] = e;
  }
  __syncthreads();
  // dedupe: keep only the LAST occurrence of each src (highest eid)
  int keep = 0;
  if (tid < k0) {
    keep = 1;
    int sv = ssrc[tid];
    for (int q = tid + 1; q < k0; ++q) if (ssrc[q] == sv) { keep = 0; break; }
  }
  u64 mask = __ballot(keep);
  int pos = __popcll(mask & ((1ull << lane) - 1ull));
  if (lane == 0 && wv < 2) wcnt[wv] = (int)__popcll(mask);
  __syncthreads();
  int base = (wv == 1) ? wcnt[0] : 0;
  if (keep) { rsrc[base + pos] = ssrc[tid]; reid[base + pos] = seid[tid]; }
  __syncthreads();
  int kd = wcnt[0] + wcnt[1];

  // each wave handles batches wv and wv+4 independently
  #pragma unroll
  for (int halfb = 0; halfb < 2; ++halfb) {
    int b = wv + halfb * 4;
    float v0 = (lane < kd)      ? eavgT[(size_t)reid[lane] * 8 + b]      : -INFINITY;
    float v1 = (lane + 64 < kd) ? eavgT[(size_t)reid[lane + 64] * 8 + b] : -INFINITY;
    float m = fmaxf(v0, v1);
    #pragma unroll
    for (int off = 32; off > 0; off >>= 1) m = fmaxf(m, __shfl_xor(m, off, 64));
    float e0 = (lane < kd)      ? expf(v0 - m) : 0.0f;
    float e1 = (lane + 64 < kd) ? expf(v1 - m) : 0.0f;
    float sum = e0 + e1;
    #pragma unroll
    for (int off = 32; off > 0; off >>= 1) sum += __shfl_xor(sum, off, 64);
    float inv = (kd > 0) ? 1.0f / sum : 0.0f;
    swgt[wv][lane] = e0 * inv;
    swgt[wv][lane + 64] = e1 * inv;
    float a0 = 0.0f, a1 = 0.0f;
    const uint32* hb = hm32 + (size_t)b * NN * (CC / 2);
    #pragma unroll 4
    for (int j = 0; j < kd; ++j) {
      float w = swgt[wv][j];
      uint32 u = hb[(size_t)rsrc[j] * (CC / 2) + lane];
      a0 += w * bf2f((ushort)(u & 0xffffu));
      a1 += w * bf2f((ushort)(u >> 16));
    }
    uint32 o = (uint32)f2bf(a0) | ((uint32)f2bf(a1) << 16);
    hout[((size_t)b * NN + d) * (CC / 2) + lane] = o;
  }
}

// ---- BN stage 1: coalesced per-128-row partials (bf16 hout, uint loads) ----
__global__ __launch_bounds__(256) void k_bnpart(const uint32* __restrict__ hout,
                                                float* __restrict__ partS,
                                                float* __restrict__ partQ) {
  int blk = blockIdx.x, tid = threadIdx.x;
  int cp = tid & 63;
  int grp = tid >> 6;
  float s0 = 0, q0 = 0, s1 = 0, q1 = 0;
  for (int i = 0; i < 32; ++i) {
    int row = blk * 128 + grp * 32 + i;
    uint32 u = hout[(size_t)row * 64 + cp];
    float v0 = bf2f((ushort)(u & 0xffffu));
    float v1 = bf2f((ushort)(u >> 16));
    s0 += v0; q0 += v0 * v0; s1 += v1; q1 += v1 * v1;
  }
  __shared__ f32x4 red[256];
  f32x4 r; r[0] = s0; r[1] = q0; r[2] = s1; r[3] = q1;
  red[tid] = r;
  __syncthreads();
  if (grp == 0) {
    f32x4 t = red[cp] + red[cp + 64] + red[cp + 128] + red[cp + 192];
    partS[blk * CC + 2 * cp]     = t[0];
    partQ[blk * CC + 2 * cp]     = t[1];
    partS[blk * CC + 2 * cp + 1] = t[2];
    partQ[blk * CC + 2 * cp + 1] = t[3];
  }
}

// ---- BN stage 2: per-channel final reduce -> scale/shift ----
__global__ __launch_bounds__(128) void k_bnstat2(const float* __restrict__ partS,
                                                 const float* __restrict__ partQ,
                                                 const float* __restrict__ gamma,
                                                 const float* __restrict__ beta,
                                                 float* __restrict__ bn) {
  int c = blockIdx.x, t = threadIdx.x;
  __shared__ float rs[128], rq[128];
  rs[t] = partS[(size_t)t * CC + c];
  rq[t] = partQ[(size_t)t * CC + c];
  __syncthreads();
  for (int off = 64; off > 0; off >>= 1) {
    if (t < off) { rs[t] += rs[t + off]; rq[t] += rq[t + off]; }
    __syncthreads();
  }
  if (t == 0) {
    float mean = rs[0] / (float)MROWS;
    float var = rq[0] / (float)MROWS - mean * mean;
    if (var < 0.0f) var = 0.0f;
    float scale = gamma[c] / sqrtf(var + BN_EPS);
    bn[c] = scale;
    bn[CC + c] = beta[c] - mean * scale;
  }
}

// ---- normalize + ELU (bf16 in, f32 out) ----
__global__ __launch_bounds__(256) void k_bnelu(const uint32* __restrict__ hout,
                                               const float* __restrict__ bn,
                                               float* __restrict__ out) {
  int p = blockIdx.x * 256 + threadIdx.x;   // pair index
  int cp = p & 63;
  uint32 u = hout[p];
  float y0 = bf2f((ushort)(u & 0xffffu)) * bn[2*cp]     + bn[CC + 2*cp];
  float y1 = bf2f((ushort)(u >> 16))     * bn[2*cp + 1] + bn[CC + 2*cp + 1];
  float2 o;
  o.x = (y0 > 0.0f) ? y0 : expm1f(y0);
  o.y = (y1 > 0.0f) ? y1 : expm1f(y1);
  *(float2*)(out + 2 * (size_t)p) = o;
}

extern "C" void kernel_launch(void* const* d_in, const int* in_sizes, int n_in,
                              void* d_out, int out_size, void* d_ws, size_t ws_size,
                              hipStream_t stream) {
  const float* x     = (const float*)d_in[0];
  const void*  ei    = d_in[1];
  const float* W     = (const float*)d_in[2];
  const float* a     = (const float*)d_in[3];
  const float* gamma = (const float*)d_in[4];
  const float* beta  = (const float*)d_in[5];
  float* out = (float*)d_out;

  char* p = (char*)d_ws;
  ushort* hm   = (ushort*)p; p += (size_t)MROWS * CC * 2;  // 4 MB (bf16)
  uint32* hout = (uint32*)p; p += (size_t)MROWS * CC * 2;  // 4 MB (bf16 pairs)
  float* eavgT = (float*)p; p += (size_t)NE * 8 * 4;       // 2 MB [e][b]
  float* s    = (float*)p; p += (size_t)MROWS * 8 * 4;     // 512 KB
  uint4* pack = (uint4*)p; p += (size_t)NFRAG * 16;        // 72 KB
  float* partS = (float*)p; p += 128 * CC * 4;             // 64 KB
  float* partQ = (float*)p; p += 128 * CC * 4;             // 64 KB
  float* bn   = (float*)p; p += 256 * 4;
  int* flag   = (int*)p;   p += 256;
  int* row_cnt  = (int*)p; p += NN * 4;
  int* row_src  = (int*)p; p += (size_t)NN * CAP * 4;      // 1 MB
  int* row_eid  = (int*)p; p += (size_t)NN * CAP * 4;      // 1 MB

  k_prep<<<32, 256, 0, stream>>>(W, a, (const int*)ei, pack, flag, row_cnt);
  k_gemm<<<MROWS / 64, 256, 0, stream>>>(x, pack, hm, s);
  k_edgefill<<<NE / 256, 256, 0, stream>>>(ei, flag, s, eavgT, row_cnt, row_src, row_eid);
  k_agg<<<NN, 256, 0, stream>>>(row_cnt, row_src, row_eid, eavgT, (const uint32*)hm, hout);
  k_bnpart<<<MROWS / 128, 256, 0, stream>>>(hout, partS, partQ);
  k_bnstat2<<<CC, 128, 0, stream>>>(partS, partQ, gamma, beta, bn);
  k_bnelu<<<(MROWS * CC / 2) / 256, 256, 0, stream>>>(hout, bn, out);
}